// Round 1
// baseline (3036.838 us; speedup 1.0000x reference)
//
#include <hip/hip_runtime.h>
#include <cstdint>
#include <cstddef>

#define N_LEVELS   16
#define LOG2_T     19
#define TABLE_SIZE (1u << LOG2_T)
#define HASH_MASK  (TABLE_SIZE - 1u)
#define PRIME1     2654435761u

#define PPB 32      // points per block
#define TPB 256     // threads per block
#define HSTRIDE 264 // padded LDS stride for hidden activations (breaks bank conflicts)

// Resolutions: floor(16 * (2^(1/3))^l) computed as fp32 (b_f32 sits just above
// the true cube root, so powers land just above exact integers -> floor hits them).
__device__ __constant__ float c_res[N_LEVELS] = {
    16.f, 20.f, 25.f, 32.f, 40.f, 50.f, 64.f, 80.f,
    101.f, 128.f, 161.f, 203.f, 256.f, 322.f, 406.f, 512.f
};

__global__ __launch_bounds__(TPB, 4)
void fused_ngp_mlp(const float* __restrict__ coord,
                   const float* __restrict__ emb,
                   const float* __restrict__ W0, const float* __restrict__ b0,
                   const float* __restrict__ W1, const float* __restrict__ b1,
                   const float* __restrict__ W2, const float* __restrict__ b2,
                   float* __restrict__ out, int npoints)
{
    __shared__ float feat[PPB][36];       // 34 used (x, y, 32 enc features)
    __shared__ float h[PPB][HSTRIDE];     // h0, then overwritten by h1

    const int t  = threadIdx.x;
    const int p0 = blockIdx.x * PPB;

    // ---------------- encoding: 8 threads per point ----------------
    {
        const int p  = t >> 3;     // 0..31
        const int k  = t & 7;      // 0..7
        const int gp = p0 + p;
        if (gp < npoints) {
            float x = coord[2 * gp + 0];
            float y = coord[2 * gp + 1];
            x = fminf(fmaxf(x, -1.0f), 1.0f);
            y = fminf(fmaxf(y, -1.0f), 1.0f);
            if (k == 0) { feat[p][0] = x; feat[p][1] = y; }
            #pragma unroll
            for (int li = 0; li < 2; ++li) {
                const int l = k + 8 * li;
                const float res  = c_res[l];
                const float grid = 2.0f / res;              // (BOX_MAX-BOX_MIN)/res
                const float tx = (x + 1.0f) / grid;         // IEEE div, matches ref
                const float ty = (y + 1.0f) / grid;
                const int bx = (int)floorf(tx);
                const int by = (int)floorf(ty);
                const float vx = (float)bx * grid - 1.0f;
                const float vy = (float)by * grid - 1.0f;
                const float wx = (x - vx) / grid;
                const float wy = (y - vy) / grid;
                const float* tab = emb + (size_t)l * (size_t)TABLE_SIZE * 2u;
                const uint32_t ux0 = (uint32_t)bx,       ux1 = (uint32_t)(bx + 1);
                const uint32_t uy0 = (uint32_t)by,       uy1 = (uint32_t)(by + 1);
                const uint32_t i00 = (ux0 ^ (uy0 * PRIME1)) & HASH_MASK;
                const uint32_t i01 = (ux0 ^ (uy1 * PRIME1)) & HASH_MASK;
                const uint32_t i10 = (ux1 ^ (uy0 * PRIME1)) & HASH_MASK;
                const uint32_t i11 = (ux1 ^ (uy1 * PRIME1)) & HASH_MASK;
                const float2 e00 = ((const float2*)tab)[i00];
                const float2 e01 = ((const float2*)tab)[i01];
                const float2 e10 = ((const float2*)tab)[i10];
                const float2 e11 = ((const float2*)tab)[i11];
                const float owx = 1.0f - wx, owy = 1.0f - wy;
                const float c00x = e00.x * owx + e10.x * wx;
                const float c01x = e01.x * owx + e11.x * wx;
                const float c00y = e00.y * owx + e10.y * wx;
                const float c01y = e01.y * owx + e11.y * wx;
                feat[p][2 + 2 * l + 0] = c00x * owy + c01x * wy;
                feat[p][2 + 2 * l + 1] = c00y * owy + c01y * wy;
            }
        } else {
            if (k == 0) { feat[p][0] = 0.f; feat[p][1] = 0.f; }
            #pragma unroll
            for (int li = 0; li < 2; ++li) {
                const int l = k + 8 * li;
                feat[p][2 + 2 * l + 0] = 0.f;
                feat[p][2 + 2 * l + 1] = 0.f;
            }
        }
    }
    __syncthreads();

    // ---------------- layer 0: 34 -> 256, relu ----------------
    // lane t owns output column j=t; feat reads are wave-uniform broadcasts.
    {
        const int j = t;
        float acc[PPB];
        const float bias = b0[j];
        #pragma unroll
        for (int p = 0; p < PPB; ++p) acc[p] = bias;
        #pragma unroll
        for (int i2 = 0; i2 < 17; ++i2) {        // 34 = 17 x float2
            const float wA = W0[(2 * i2 + 0) * 256 + j];
            const float wB = W0[(2 * i2 + 1) * 256 + j];
            #pragma unroll
            for (int p = 0; p < PPB; ++p) {
                const float2 fv = *(const float2*)&feat[p][2 * i2];
                acc[p] += fv.x * wA + fv.y * wB;
            }
        }
        #pragma unroll
        for (int p = 0; p < PPB; ++p)
            h[p][j] = fmaxf(acc[p], 0.0f);
    }
    __syncthreads();

    // ---------------- layer 1: 256 -> 256, relu ----------------
    {
        const int j = t;
        float acc[PPB];
        const float bias = b1[j];
        #pragma unroll
        for (int p = 0; p < PPB; ++p) acc[p] = bias;
        for (int i = 0; i < 256; i += 4) {
            const float w0v = W1[(i + 0) * 256 + j];
            const float w1v = W1[(i + 1) * 256 + j];
            const float w2v = W1[(i + 2) * 256 + j];
            const float w3v = W1[(i + 3) * 256 + j];
            #pragma unroll
            for (int p = 0; p < PPB; ++p) {
                const float4 hv = *(const float4*)&h[p][i];  // broadcast b128
                acc[p] += hv.x * w0v + hv.y * w1v + hv.z * w2v + hv.w * w3v;
            }
        }
        __syncthreads();   // everyone done READING h0 before overwrite
        #pragma unroll
        for (int p = 0; p < PPB; ++p)
            h[p][j] = fmaxf(acc[p], 0.0f);       // h1 overwrites h0
    }
    __syncthreads();

    // ---------------- layer 2: 256 -> 3, sigmoid ----------------
    // 8 threads per point compute strided partial dots; reduce via LDS.
    float (*part)[8][3] = (float(*)[8][3])&feat[0][0];   // reuse feat buffer (768 floats)
    {
        const int p = t >> 3;
        const int k = t & 7;
        float s0 = 0.f, s1 = 0.f, s2 = 0.f;
        #pragma unroll 4
        for (int i = k; i < 256; i += 8) {
            const float hv = h[p][i];
            s0 += hv * W2[i * 3 + 0];
            s1 += hv * W2[i * 3 + 1];
            s2 += hv * W2[i * 3 + 2];
        }
        part[p][k][0] = s0;
        part[p][k][1] = s1;
        part[p][k][2] = s2;
    }
    __syncthreads();

    if (t < PPB * 3) {
        const int p = t / 3;
        const int c = t % 3;
        const int gp = p0 + p;
        if (gp < npoints) {
            float s = b2[c];
            #pragma unroll
            for (int k = 0; k < 8; ++k) s += part[p][k][c];
            const float r = 1.0f / (1.0f + expf(-s));
            out[(size_t)gp * 3 + c] = r;
        }
    }
}

extern "C" void kernel_launch(void* const* d_in, const int* in_sizes, int n_in,
                              void* d_out, int out_size, void* d_ws, size_t ws_size,
                              hipStream_t stream) {
    const float* coord = (const float*)d_in[0];
    const float* emb   = (const float*)d_in[1];
    const float* W0    = (const float*)d_in[2];
    const float* b0    = (const float*)d_in[3];
    const float* W1    = (const float*)d_in[4];
    const float* b1    = (const float*)d_in[5];
    const float* W2    = (const float*)d_in[6];
    const float* b2    = (const float*)d_in[7];
    float* out = (float*)d_out;

    const int npoints = in_sizes[0] / 2;
    const int blocks  = (npoints + PPB - 1) / PPB;

    hipLaunchKernelGGL(fused_ngp_mlp, dim3(blocks), dim3(TPB), 0, stream,
                       coord, emb, W0, b0, W1, b1, W2, b2, out, npoints);
}

// Round 2
// 388.366 us; speedup vs baseline: 7.8195x; 7.8195x over previous
//
#include <hip/hip_runtime.h>
#include <cstdint>
#include <cstddef>

#define N_LEVELS   16
#define LOG2_T     19
#define TABLE_SIZE (1u << LOG2_T)
#define HASH_MASK  (TABLE_SIZE - 1u)
#define PRIME1     2654435761u

#define TPB 256
#define BT  64          // points per block
#define FSTRIDE 72      // feat row stride (ushort units): 64 + 8 pad
#define HSTRIDE 264     // h row stride (ushort units): 256 + 8 pad

typedef __attribute__((ext_vector_type(8))) short short8;
typedef __attribute__((ext_vector_type(4))) float floatx4;

// floor(16 * (2^(1/3))^l) in fp32 lands exactly on these integers
__device__ __constant__ float c_res[N_LEVELS] = {
    16.f, 20.f, 25.f, 32.f, 40.f, 50.f, 64.f, 80.f,
    101.f, 128.f, 161.f, 203.f, 256.f, 322.f, 406.f, 512.f
};

__device__ __forceinline__ unsigned short f2bf(float x) {
    union { float f; uint32_t u; } v; v.f = x;
    const uint32_t u = v.u;
    return (unsigned short)((u + 0x7fffu + ((u >> 16) & 1u)) >> 16);  // RNE
}

// ---------------- weight packing into MFMA B-operand fragments ----------------
// 16x16x32 B-frag: lane (q=l>>4, r=l&15) holds B[k = kt*32 + q*8 + j][n = nt*16 + r], j=0..7
// ws layout (ushort units): W0p frags[kt<2][nt<16] @ 0 ; W1p frags[8][16] @ 32*1024 ;
//                           W2p frags[8][1] @ 160*1024.  One wave packs one frag.
__global__ void pack_weights(const float* __restrict__ W0,
                             const float* __restrict__ W1,
                             const float* __restrict__ W2,
                             unsigned short* __restrict__ ws)
{
    const int f = blockIdx.x;       // 0..167
    const int lane = threadIdx.x;   // 0..63
    const int q = lane >> 4, r = lane & 15;
    int layer, kt, nt;
    if (f < 32)       { layer = 0; kt = f >> 4;        nt = f & 15; }
    else if (f < 160) { layer = 1; kt = (f - 32) >> 4; nt = (f - 32) & 15; }
    else              { layer = 2; kt = f - 160;       nt = 0; }
    unsigned short vals[8];
    #pragma unroll
    for (int j = 0; j < 8; ++j) {
        const int k = kt * 32 + q * 8 + j;
        const int n = nt * 16 + r;
        float v = 0.f;
        if (layer == 0) {
            // feat order: [enc0..enc31, x, y, zeros]; original W0 rows: [x, y, enc0..enc31]
            if (k < 32)       v = W0[(2 + k) * 256 + n];
            else if (k == 32) v = W0[0 * 256 + n];
            else if (k == 33) v = W0[1 * 256 + n];
        } else if (layer == 1) {
            v = W1[k * 256 + n];
        } else {
            if (n < 3) v = W2[k * 3 + n];
        }
        vals[j] = f2bf(v);
    }
    uint4 pk;
    pk.x = (uint32_t)vals[0] | ((uint32_t)vals[1] << 16);
    pk.y = (uint32_t)vals[2] | ((uint32_t)vals[3] << 16);
    pk.z = (uint32_t)vals[4] | ((uint32_t)vals[5] << 16);
    pk.w = (uint32_t)vals[6] | ((uint32_t)vals[7] << 16);
    *(uint4*)(ws + (size_t)f * 1024 + lane * 8) = pk;
}

// ---------------- fused encoding + MLP ----------------
__global__ __launch_bounds__(TPB, 2)
void fused_ngp_mlp(const float* __restrict__ coord,
                   const float* __restrict__ emb,
                   const unsigned short* __restrict__ wpack,
                   const float* __restrict__ b0,
                   const float* __restrict__ b1,
                   const float* __restrict__ b2,
                   float* __restrict__ out, int npoints)
{
    __shared__ unsigned short feat[BT][FSTRIDE];  // bf16 bits: [enc0..31, x, y, 0-pad..63]
    __shared__ unsigned short h[BT][HSTRIDE];     // h0, then h1

    const int t = threadIdx.x;
    const int p0 = blockIdx.x * BT;
    const int wave = t >> 6;
    const int lane = t & 63;
    const int q = lane >> 4, r = lane & 15;

    // ---------- phase 1: hash-grid encoding (4 threads/point, 4 levels each) ----------
    {
        const int p = t >> 2;
        const int k = t & 3;
        const int gp = p0 + p;
        float x = 0.f, y = 0.f;
        if (gp < npoints) {
            x = coord[2 * gp + 0]; y = coord[2 * gp + 1];
            x = fminf(fmaxf(x, -1.f), 1.f);
            y = fminf(fmaxf(y, -1.f), 1.f);
        }
        if (k == 0) {
            feat[p][32] = f2bf(x); feat[p][33] = f2bf(y);
            *(uint32_t*)&feat[p][34] = 0u;
            *(uint32_t*)&feat[p][36] = 0u;
            *(uint32_t*)&feat[p][38] = 0u;
        } else {
            const uint4 z = {0u, 0u, 0u, 0u};
            *(uint4*)&feat[p][40 + 8 * (k - 1)] = z;   // covers 40..63
        }
        #pragma unroll
        for (int i = 0; i < 4; ++i) {
            const int l = 4 * k + i;
            const float res  = c_res[l];
            const float grid = 2.0f / res;             // IEEE div (matches ref exactly)
            const float invg = res * 0.5f;             // exact
            const float tx = (x + 1.0f) / grid;        // IEEE div feeds floor -> exact match
            const float ty = (y + 1.0f) / grid;
            const int bx = (int)floorf(tx);
            const int by = (int)floorf(ty);
            const float vx = (float)bx * grid - 1.0f;
            const float vy = (float)by * grid - 1.0f;
            const float wx = (x - vx) * invg;
            const float wy = (y - vy) * invg;
            const float2* tab = (const float2*)emb + (size_t)l * TABLE_SIZE;
            const uint32_t ux0 = (uint32_t)bx, ux1 = (uint32_t)(bx + 1);
            const uint32_t hy0 = (uint32_t)by * PRIME1;
            const uint32_t hy1 = (uint32_t)(by + 1) * PRIME1;
            const float2 e00 = tab[(ux0 ^ hy0) & HASH_MASK];
            const float2 e01 = tab[(ux0 ^ hy1) & HASH_MASK];
            const float2 e10 = tab[(ux1 ^ hy0) & HASH_MASK];
            const float2 e11 = tab[(ux1 ^ hy1) & HASH_MASK];
            const float owx = 1.f - wx, owy = 1.f - wy;
            const float f0 = (e00.x * owx + e10.x * wx) * owy + (e01.x * owx + e11.x * wx) * wy;
            const float f1 = (e00.y * owx + e10.y * wx) * owy + (e01.y * owx + e11.y * wx) * wy;
            const uint32_t pkd = (uint32_t)f2bf(f0) | ((uint32_t)f2bf(f1) << 16);
            *(uint32_t*)&feat[p][8 * k + 2 * i] = pkd;  // byte 16k+4i, 4-aligned
        }
    }
    __syncthreads();

    const unsigned short* w0p = wpack;
    const unsigned short* w1p = wpack + 32 * 1024;
    const unsigned short* w2p = wpack + 160 * 1024;

    // ---------- phase 2: layer 0 (K=64 padded -> 256), bias+relu -> h0 ----------
    {
        floatx4 acc[4][4];
        #pragma unroll
        for (int mt = 0; mt < 4; ++mt)
            #pragma unroll
            for (int n = 0; n < 4; ++n)
                acc[mt][n] = floatx4{0.f, 0.f, 0.f, 0.f};
        #pragma unroll
        for (int kt = 0; kt < 2; ++kt) {
            short8 a[4], b[4];
            #pragma unroll
            for (int mt = 0; mt < 4; ++mt)
                a[mt] = *(const short8*)&feat[16 * mt + r][kt * 32 + q * 8];
            #pragma unroll
            for (int n = 0; n < 4; ++n)
                b[n] = *(const short8*)(w0p + (size_t)(kt * 16 + wave * 4 + n) * 1024 + lane * 8);
            #pragma unroll
            for (int mt = 0; mt < 4; ++mt)
                #pragma unroll
                for (int n = 0; n < 4; ++n)
                    acc[mt][n] = __builtin_amdgcn_mfma_f32_16x16x32_bf16(a[mt], b[n], acc[mt][n], 0, 0, 0);
        }
        #pragma unroll
        for (int n = 0; n < 4; ++n) {
            const float bias = b0[(wave * 4 + n) * 16 + r];
            #pragma unroll
            for (int mt = 0; mt < 4; ++mt)
                #pragma unroll
                for (int reg = 0; reg < 4; ++reg) {
                    const float v = acc[mt][n][reg] + bias;
                    h[16 * mt + 4 * q + reg][(wave * 4 + n) * 16 + r] = f2bf(fmaxf(v, 0.f));
                }
        }
    }
    __syncthreads();

    // ---------- phase 3: layer 1 (256 -> 256), bias+relu -> h1 ----------
    {
        floatx4 acc[4][4];
        #pragma unroll
        for (int mt = 0; mt < 4; ++mt)
            #pragma unroll
            for (int n = 0; n < 4; ++n)
                acc[mt][n] = floatx4{0.f, 0.f, 0.f, 0.f};
        #pragma unroll 2
        for (int kt = 0; kt < 8; ++kt) {
            short8 a[4], b[4];
            #pragma unroll
            for (int mt = 0; mt < 4; ++mt)
                a[mt] = *(const short8*)&h[16 * mt + r][kt * 32 + q * 8];
            #pragma unroll
            for (int n = 0; n < 4; ++n)
                b[n] = *(const short8*)(w1p + (size_t)(kt * 16 + wave * 4 + n) * 1024 + lane * 8);
            #pragma unroll
            for (int mt = 0; mt < 4; ++mt)
                #pragma unroll
                for (int n = 0; n < 4; ++n)
                    acc[mt][n] = __builtin_amdgcn_mfma_f32_16x16x32_bf16(a[mt], b[n], acc[mt][n], 0, 0, 0);
        }
        __syncthreads();   // all reads of h0 complete before overwrite
        #pragma unroll
        for (int n = 0; n < 4; ++n) {
            const float bias = b1[(wave * 4 + n) * 16 + r];
            #pragma unroll
            for (int mt = 0; mt < 4; ++mt)
                #pragma unroll
                for (int reg = 0; reg < 4; ++reg) {
                    const float v = acc[mt][n][reg] + bias;
                    h[16 * mt + 4 * q + reg][(wave * 4 + n) * 16 + r] = f2bf(fmaxf(v, 0.f));
                }
        }
    }
    __syncthreads();

    // ---------- phase 4: layer 2 (256 -> 3), sigmoid, store ----------
    {
        floatx4 acc = floatx4{0.f, 0.f, 0.f, 0.f};
        #pragma unroll
        for (int kt = 0; kt < 8; ++kt) {
            const short8 a = *(const short8*)&h[16 * wave + r][kt * 32 + q * 8];
            const short8 b = *(const short8*)(w2p + (size_t)kt * 1024 + lane * 8);
            acc = __builtin_amdgcn_mfma_f32_16x16x32_bf16(a, b, acc, 0, 0, 0);
        }
        const float bv = (r < 3) ? b2[r] : 0.f;
        #pragma unroll
        for (int reg = 0; reg < 4; ++reg) {
            const int row = 16 * wave + 4 * q + reg;
            const int gp = p0 + row;
            if (r < 3 && gp < npoints) {
                const float s = acc[reg] + bv;
                out[(size_t)gp * 3 + r] = 1.f / (1.f + expf(-s));
            }
        }
    }
}

extern "C" void kernel_launch(void* const* d_in, const int* in_sizes, int n_in,
                              void* d_out, int out_size, void* d_ws, size_t ws_size,
                              hipStream_t stream) {
    const float* coord = (const float*)d_in[0];
    const float* emb   = (const float*)d_in[1];
    const float* W0    = (const float*)d_in[2];
    const float* b0    = (const float*)d_in[3];
    const float* W1    = (const float*)d_in[4];
    const float* b1    = (const float*)d_in[5];
    const float* W2    = (const float*)d_in[6];
    const float* b2    = (const float*)d_in[7];
    float* out = (float*)d_out;
    unsigned short* ws = (unsigned short*)d_ws;

    const int npoints = in_sizes[0] / 2;
    const int blocks  = (npoints + BT - 1) / BT;

    hipLaunchKernelGGL(pack_weights, dim3(168), dim3(64), 0, stream, W0, W1, W2, ws);
    hipLaunchKernelGGL(fused_ngp_mlp, dim3(blocks), dim3(TPB), 0, stream,
                       coord, emb, ws, b0, b1, b2, out, npoints);
}

// Round 3
// 378.655 us; speedup vs baseline: 8.0201x; 1.0256x over previous
//
#include <hip/hip_runtime.h>
#include <hip/hip_bf16.h>
#include <cstdint>
#include <cstddef>

#define N_LEVELS   16
#define LOG2_T     19
#define TABLE_SIZE (1u << LOG2_T)
#define HASH_MASK  (TABLE_SIZE - 1u)
#define PRIME1     2654435761u

#define TPB 256
#define BT  64          // points per block
#define FSTRIDE 72      // feat row stride (ushort): 64 + 8 pad (144 B == 4 banks mod 32 -> conflict-free octets)
#define HSTRIDE 264     // h row stride (ushort): 256 + 8 pad (528 B == 4 banks mod 32)

typedef __attribute__((ext_vector_type(8))) short short8;
typedef __attribute__((ext_vector_type(4))) float floatx4;

// floor(16 * (2^(1/3))^l) in fp32 lands exactly on these integers
__device__ __constant__ float c_res[N_LEVELS] = {
    16.f, 20.f, 25.f, 32.f, 40.f, 50.f, 64.f, 80.f,
    101.f, 128.f, 161.f, 203.f, 256.f, 322.f, 406.f, 512.f
};

__device__ __forceinline__ unsigned short f2bf(float x) {
    union { float f; uint32_t u; } v; v.f = x;
    const uint32_t u = v.u;
    return (unsigned short)((u + 0x7fffu + ((u >> 16) & 1u)) >> 16);  // RNE
}

__device__ __forceinline__ uint32_t pk_bf16(float a, float b) {
#if __has_builtin(__builtin_amdgcn_cvt_pk_bf16_f32)
    typedef __attribute__((ext_vector_type(2))) __bf16 bf16x2;
    bf16x2 v = __builtin_amdgcn_cvt_pk_bf16_f32(a, b);
    uint32_t u; __builtin_memcpy(&u, &v, 4); return u;
#else
    return (uint32_t)f2bf(a) | ((uint32_t)f2bf(b) << 16);
#endif
}

// ---------------- weight packing into MFMA fragments ----------------
// Fragment for (tile, ktile): lane (q=l>>4, r=l&15) holds W[k = kt*32 + q*8 + j][col = tile*16 + r].
// Used as the MFMA *A* operand (A[m=r][k=q*8+j] = W^T[m][k]) — same bytes as a B-frag of W.
__global__ void pack_weights(const float* __restrict__ W0,
                             const float* __restrict__ W1,
                             const float* __restrict__ W2,
                             unsigned short* __restrict__ ws)
{
    const int f = blockIdx.x;       // 0..167
    const int lane = threadIdx.x;   // 0..63
    const int q = lane >> 4, r = lane & 15;
    int layer, kt, nt;
    if (f < 32)       { layer = 0; kt = f >> 4;        nt = f & 15; }
    else if (f < 160) { layer = 1; kt = (f - 32) >> 4; nt = (f - 32) & 15; }
    else              { layer = 2; kt = f - 160;       nt = 0; }
    unsigned short vals[8];
    #pragma unroll
    for (int j = 0; j < 8; ++j) {
        const int k = kt * 32 + q * 8 + j;
        const int n = nt * 16 + r;
        float v = 0.f;
        if (layer == 0) {
            // feat order: [enc0..enc31, x, y, zeros]; original W0 rows: [x, y, enc0..enc31]
            if (k < 32)       v = W0[(2 + k) * 256 + n];
            else if (k == 32) v = W0[0 * 256 + n];
            else if (k == 33) v = W0[1 * 256 + n];
        } else if (layer == 1) {
            v = W1[k * 256 + n];
        } else {
            if (n < 3) v = W2[k * 3 + n];
        }
        vals[j] = f2bf(v);
    }
    uint4 pk;
    pk.x = (uint32_t)vals[0] | ((uint32_t)vals[1] << 16);
    pk.y = (uint32_t)vals[2] | ((uint32_t)vals[3] << 16);
    pk.z = (uint32_t)vals[4] | ((uint32_t)vals[5] << 16);
    pk.w = (uint32_t)vals[6] | ((uint32_t)vals[7] << 16);
    *(uint4*)(ws + (size_t)f * 1024 + lane * 8) = pk;
}

// ---------------- fused encoding + MLP ----------------
__global__ __launch_bounds__(TPB, 2)
void fused_ngp_mlp(const float* __restrict__ coord,
                   const float* __restrict__ emb,
                   const unsigned short* __restrict__ wpack,
                   const float* __restrict__ b0,
                   const float* __restrict__ b1,
                   const float* __restrict__ b2,
                   float* __restrict__ out, int npoints)
{
    __shared__ unsigned short feat[BT][FSTRIDE];  // bf16: [enc0..31, x, y, 0-pad..63]
    __shared__ unsigned short h[BT][HSTRIDE];     // h0, then h1; layout [point][neuron]

    const int t = threadIdx.x;
    const int p0 = blockIdx.x * BT;
    const int wave = t >> 6;
    const int lane = t & 63;
    const int q = lane >> 4, r = lane & 15;

    // ---------- phase 1: hash-grid encoding (4 threads/point, 4 levels each) ----------
    {
        const int p = t >> 2;
        const int k = t & 3;
        const int gp = p0 + p;
        float x = 0.f, y = 0.f;
        if (gp < npoints) {
            x = coord[2 * gp + 0]; y = coord[2 * gp + 1];
            x = fminf(fmaxf(x, -1.f), 1.f);
            y = fminf(fmaxf(y, -1.f), 1.f);
        }
        if (k == 0) {
            feat[p][32] = f2bf(x); feat[p][33] = f2bf(y);
            *(uint32_t*)&feat[p][34] = 0u;
            *(uint32_t*)&feat[p][36] = 0u;
            *(uint32_t*)&feat[p][38] = 0u;
        } else {
            const uint4 z = {0u, 0u, 0u, 0u};
            *(uint4*)&feat[p][40 + 8 * (k - 1)] = z;   // covers 40..63
        }
        #pragma unroll
        for (int i = 0; i < 4; ++i) {
            const int l = 4 * k + i;
            const float res  = c_res[l];
            const float grid = 2.0f / res;             // IEEE div of constants (matches ref)
            const float invg = res * 0.5f;             // exact
            const float tx = (x + 1.0f) / grid;        // IEEE div feeds floor -> exact cell match
            const float ty = (y + 1.0f) / grid;
            const int bx = (int)floorf(tx);
            const int by = (int)floorf(ty);
            const float vx = (float)bx * grid - 1.0f;
            const float vy = (float)by * grid - 1.0f;
            const float wx = (x - vx) * invg;
            const float wy = (y - vy) * invg;
            const float2* tab = (const float2*)emb + (size_t)l * TABLE_SIZE;
            const uint32_t ux0 = (uint32_t)bx, ux1 = (uint32_t)(bx + 1);
            const uint32_t hy0 = (uint32_t)by * PRIME1;
            const uint32_t hy1 = (uint32_t)(by + 1) * PRIME1;
            const float2 e00 = tab[(ux0 ^ hy0) & HASH_MASK];
            const float2 e01 = tab[(ux0 ^ hy1) & HASH_MASK];
            const float2 e10 = tab[(ux1 ^ hy0) & HASH_MASK];
            const float2 e11 = tab[(ux1 ^ hy1) & HASH_MASK];
            const float owx = 1.f - wx, owy = 1.f - wy;
            const float f0 = (e00.x * owx + e10.x * wx) * owy + (e01.x * owx + e11.x * wx) * wy;
            const float f1 = (e00.y * owx + e10.y * wx) * owy + (e01.y * owx + e11.y * wx) * wy;
            *(uint32_t*)&feat[p][8 * k + 2 * i] = pk_bf16(f0, f1);
        }
    }
    __syncthreads();

    const unsigned short* w0p = wpack;
    const unsigned short* w1p = wpack + 32 * 1024;
    const unsigned short* w2p = wpack + 160 * 1024;

    // ---------- phase 2: layer 0 (K=64 padded), W^T x feat^T -> h0[point][neuron] ----------
    {
        floatx4 acc[4][4];   // [mti (neuron tile)][nt (point tile)]
        #pragma unroll
        for (int mti = 0; mti < 4; ++mti)
            #pragma unroll
            for (int nt = 0; nt < 4; ++nt)
                acc[mti][nt] = floatx4{0.f, 0.f, 0.f, 0.f};
        #pragma unroll
        for (int kt = 0; kt < 2; ++kt) {
            short8 a[4], b[4];
            #pragma unroll
            for (int mti = 0; mti < 4; ++mti)
                a[mti] = *(const short8*)(w0p + (size_t)(kt * 16 + wave * 4 + mti) * 1024 + lane * 8);
            #pragma unroll
            for (int nt = 0; nt < 4; ++nt)
                b[nt] = *(const short8*)&feat[16 * nt + r][kt * 32 + q * 8];
            #pragma unroll
            for (int mti = 0; mti < 4; ++mti)
                #pragma unroll
                for (int nt = 0; nt < 4; ++nt)
                    acc[mti][nt] = __builtin_amdgcn_mfma_f32_16x16x32_bf16(a[mti], b[nt], acc[mti][nt], 0, 0, 0);
        }
        // C[m=neuron=(wave*4+mti)*16+4q+reg][n=point=16nt+r] -> 4 contiguous columns: b64 write
        #pragma unroll
        for (int mti = 0; mti < 4; ++mti) {
            const int col = (wave * 4 + mti) * 16 + 4 * q;
            const float4 bias = *(const float4*)&b0[col];
            #pragma unroll
            for (int nt = 0; nt < 4; ++nt) {
                const floatx4 a = acc[mti][nt];
                uint2 v;
                v.x = pk_bf16(fmaxf(a[0] + bias.x, 0.f), fmaxf(a[1] + bias.y, 0.f));
                v.y = pk_bf16(fmaxf(a[2] + bias.z, 0.f), fmaxf(a[3] + bias.w, 0.f));
                *(uint2*)&h[16 * nt + r][col] = v;
            }
        }
    }
    __syncthreads();

    // ---------- phase 3: layer 1 (256 -> 256) ----------
    {
        floatx4 acc[4][4];
        #pragma unroll
        for (int mti = 0; mti < 4; ++mti)
            #pragma unroll
            for (int nt = 0; nt < 4; ++nt)
                acc[mti][nt] = floatx4{0.f, 0.f, 0.f, 0.f};
        #pragma unroll 2
        for (int kt = 0; kt < 8; ++kt) {
            short8 a[4], b[4];
            #pragma unroll
            for (int mti = 0; mti < 4; ++mti)
                a[mti] = *(const short8*)(w1p + (size_t)(kt * 16 + wave * 4 + mti) * 1024 + lane * 8);
            #pragma unroll
            for (int nt = 0; nt < 4; ++nt)
                b[nt] = *(const short8*)&h[16 * nt + r][kt * 32 + q * 8];
            #pragma unroll
            for (int mti = 0; mti < 4; ++mti)
                #pragma unroll
                for (int nt = 0; nt < 4; ++nt)
                    acc[mti][nt] = __builtin_amdgcn_mfma_f32_16x16x32_bf16(a[mti], b[nt], acc[mti][nt], 0, 0, 0);
        }
        __syncthreads();   // all reads of h0 done before overwrite
        #pragma unroll
        for (int mti = 0; mti < 4; ++mti) {
            const int col = (wave * 4 + mti) * 16 + 4 * q;
            const float4 bias = *(const float4*)&b1[col];
            #pragma unroll
            for (int nt = 0; nt < 4; ++nt) {
                const floatx4 a = acc[mti][nt];
                uint2 v;
                v.x = pk_bf16(fmaxf(a[0] + bias.x, 0.f), fmaxf(a[1] + bias.y, 0.f));
                v.y = pk_bf16(fmaxf(a[2] + bias.z, 0.f), fmaxf(a[3] + bias.w, 0.f));
                *(uint2*)&h[16 * nt + r][col] = v;
            }
        }
    }
    __syncthreads();

    // ---------- phase 4: layer 2 (256 -> 3), sigmoid, store ----------
    {
        floatx4 acc = floatx4{0.f, 0.f, 0.f, 0.f};
        #pragma unroll
        for (int kt = 0; kt < 8; ++kt) {
            const short8 a = *(const short8*)(w2p + (size_t)kt * 1024 + lane * 8);
            const short8 b = *(const short8*)&h[16 * wave + r][kt * 32 + q * 8];
            acc = __builtin_amdgcn_mfma_f32_16x16x32_bf16(a, b, acc, 0, 0, 0);
        }
        // C[m=4q+reg][n=16*wave+r]: only q==0, reg<3 are real outputs
        if (q == 0) {
            const int gp = p0 + 16 * wave + r;
            if (gp < npoints) {
                #pragma unroll
                for (int reg = 0; reg < 3; ++reg) {
                    const float s = acc[reg] + b2[reg];
                    out[(size_t)gp * 3 + reg] = 1.f / (1.f + expf(-s));
                }
            }
        }
    }
}

extern "C" void kernel_launch(void* const* d_in, const int* in_sizes, int n_in,
                              void* d_out, int out_size, void* d_ws, size_t ws_size,
                              hipStream_t stream) {
    const float* coord = (const float*)d_in[0];
    const float* emb   = (const float*)d_in[1];
    const float* W0    = (const float*)d_in[2];
    const float* b0    = (const float*)d_in[3];
    const float* W1    = (const float*)d_in[4];
    const float* b1    = (const float*)d_in[5];
    const float* W2    = (const float*)d_in[6];
    const float* b2    = (const float*)d_in[7];
    float* out = (float*)d_out;
    unsigned short* ws = (unsigned short*)d_ws;

    const int npoints = in_sizes[0] / 2;
    const int blocks  = (npoints + BT - 1) / BT;

    hipLaunchKernelGGL(pack_weights, dim3(168), dim3(64), 0, stream, W0, W1, W2, ws);
    hipLaunchKernelGGL(fused_ngp_mlp, dim3(blocks), dim3(TPB), 0, stream,
                       coord, emb, ws, b0, b1, b2, out, npoints);
}